// Round 3
// baseline (170.002 us; speedup 1.0000x reference)
//
#include <hip/hip_runtime.h>

#define P 10
#define D 1024
#define NROWS 16384

typedef float nfloat4 __attribute__((ext_vector_type(4)));   // clang-native for nontemporal builtins

// ---------------------------------------------------------------------------
// Column mapping for the main kernel:
//   k = e_hi*256 + lane*4 + e_lo,  e = e_hi*4 + e_lo,  e in [0,16), lane in [0,64)
//   k bits: [1:0]=e_lo  [7:2]=lane  [9:8]=e_hi
// Stage j flips bit j of k:
//   j=0,1  -> e_lo bits  -> intra-thread, partner e^1 / e^2
//   j=2..7 -> lane bits  -> __shfl_xor with mask 1<<(j-2)
//   j=8,9  -> e_hi bits  -> intra-thread, partner e^4 / e^8
//
// Coef table is stored SWIZZLED to this mapping:
//   coef[j*D + e*64 + lane] = (u_re, u_im, v_re, v_im) for column k(e,lane)
// so every coef load is consecutive-lane coalesced (16B/lane contiguous).
// psi epilogue rotation is folded into the stage-9 coefficients.
// ---------------------------------------------------------------------------
__global__ void coef_kernel(const float* __restrict__ theta,
                            const float* __restrict__ phi,
                            const float* __restrict__ psi,
                            float4* __restrict__ coef) {
    int idx = blockIdx.x * blockDim.x + threadIdx.x;
    if (idx >= P * D) return;
    int j = idx >> 10;
    int slot = idx & (D - 1);
    int e = slot >> 6;
    int lane = slot & 63;
    int k = ((e >> 2) << 8) + (lane << 2) + (e & 3);   // column this slot serves
    int b = (k >> j) & 1;
    unsigned lowmask = (1u << j) - 1u;
    unsigned m = ((unsigned)k & lowmask) | (((unsigned)k >> 1) & ~lowmask); // delete bit j
    float th = theta[j * (D / 2) + m];
    float ph = phi[j * (D / 2) + m];
    float h = th * 0.5f;
    float s1 = sinf(h), c1 = cosf(h);
    float s2 = sinf(h + ph), c2 = cosf(h + ph);
    float ur, ui, vr, vi;
    if (b) { ur =  s1 * s1; vr = -c1 * s2; ui = -c1 * s1; vi = c1 * c2; }
    else   { ur = -s1 * s2; vr = -c1 * s1; ui =  s1 * c2; vi = c1 * c1; }
    if (j == P - 1) {
        float ps = psi[k];
        float cp = cosf(ps), sp = sinf(ps);
        float ur2 = cp * ur - sp * ui, ui2 = sp * ur + cp * ui;
        float vr2 = cp * vr - sp * vi, vi2 = sp * vr + cp * vi;
        ur = ur2; ui = ui2; vr = vr2; vi = vi2;
    }
    coef[idx] = make_float4(ur, ui, vr, vi);
}

// ---------------------------------------------------------------------------
// Intra-thread butterfly stage: partner differs in a bit of e (mask PM).
// ---------------------------------------------------------------------------
template <int J, int PM>
__device__ __forceinline__ void stage_intra(float (&ra)[16], float (&ia)[16],
                                            float (&rb)[16], float (&ib)[16],
                                            const float4* __restrict__ coef, int lane) {
    const float4* cj = coef + J * D + lane;
#pragma unroll
    for (int e0 = 0; e0 < 16; ++e0) {
        if (e0 & PM) continue;
        const int e1 = e0 | PM;
        float4 c0 = cj[e0 * 64];
        float4 c1 = cj[e1 * 64];
        float ar0 = ra[e0], ai0 = ia[e0], ar1 = ra[e1], ai1 = ia[e1];
        float br0 = rb[e0], bi0 = ib[e0], br1 = rb[e1], bi1 = ib[e1];
        ra[e0] = c0.x * ar0 - c0.y * ai0 + c0.z * ar1 - c0.w * ai1;
        ia[e0] = c0.x * ai0 + c0.y * ar0 + c0.z * ai1 + c0.w * ar1;
        ra[e1] = c1.x * ar1 - c1.y * ai1 + c1.z * ar0 - c1.w * ai0;
        ia[e1] = c1.x * ai1 + c1.y * ar1 + c1.z * ai0 + c1.w * ar0;
        rb[e0] = c0.x * br0 - c0.y * bi0 + c0.z * br1 - c0.w * bi1;
        ib[e0] = c0.x * bi0 + c0.y * br0 + c0.z * bi1 + c0.w * br1;
        rb[e1] = c1.x * br1 - c1.y * bi1 + c1.z * br0 - c1.w * bi0;
        ib[e1] = c1.x * bi1 + c1.y * br1 + c1.z * bi0 + c1.w * br0;
    }
}

// ---------------------------------------------------------------------------
// Cross-lane butterfly stage: partner differs in lane bit (J-2).
// ---------------------------------------------------------------------------
template <int J>
__device__ __forceinline__ void stage_shfl(float (&ra)[16], float (&ia)[16],
                                           float (&rb)[16], float (&ib)[16],
                                           const float4* __restrict__ coef, int lane) {
    const int mask = 1 << (J - 2);
    const float4* cj = coef + J * D + lane;
#pragma unroll
    for (int e = 0; e < 16; ++e) {
        float4 c = cj[e * 64];
        float sra = __shfl_xor(ra[e], mask);
        float sia = __shfl_xor(ia[e], mask);
        float srb = __shfl_xor(rb[e], mask);
        float sib = __shfl_xor(ib[e], mask);
        float nra = c.x * ra[e] - c.y * ia[e] + c.z * sra - c.w * sia;
        float nia = c.x * ia[e] + c.y * ra[e] + c.z * sia + c.w * sra;
        float nrb = c.x * rb[e] - c.y * ib[e] + c.z * srb - c.w * sib;
        float nib = c.x * ib[e] + c.y * rb[e] + c.z * sib + c.w * srb;
        ra[e] = nra; ia[e] = nia; rb[e] = nrb; ib[e] = nib;
    }
}

__global__ __launch_bounds__(256, 5) void fft_kernel(const float* __restrict__ X,
                                                     const float4* __restrict__ coef,
                                                     float* __restrict__ out) {
    const int lane = threadIdx.x & 63;
    const int wave = threadIdx.x >> 6;
    const long rowbase = (long)blockIdx.x * 8 + (long)wave * 2;
    const float* x0 = X + rowbase * 2048 + lane * 4;
    const float* x1 = x0 + 2048;

    float ra[16], ia[16], rb[16], ib[16];
#pragma unroll
    for (int eh = 0; eh < 4; ++eh) {
        float4 v0r = *(const float4*)(x0 + eh * 256);
        float4 v0i = *(const float4*)(x0 + 1024 + eh * 256);
        float4 v1r = *(const float4*)(x1 + eh * 256);
        float4 v1i = *(const float4*)(x1 + 1024 + eh * 256);
        ra[eh * 4 + 0] = v0r.x; ra[eh * 4 + 1] = v0r.y; ra[eh * 4 + 2] = v0r.z; ra[eh * 4 + 3] = v0r.w;
        ia[eh * 4 + 0] = v0i.x; ia[eh * 4 + 1] = v0i.y; ia[eh * 4 + 2] = v0i.z; ia[eh * 4 + 3] = v0i.w;
        rb[eh * 4 + 0] = v1r.x; rb[eh * 4 + 1] = v1r.y; rb[eh * 4 + 2] = v1r.z; rb[eh * 4 + 3] = v1r.w;
        ib[eh * 4 + 0] = v1i.x; ib[eh * 4 + 1] = v1i.y; ib[eh * 4 + 2] = v1i.z; ib[eh * 4 + 3] = v1i.w;
    }

    stage_intra<0, 1>(ra, ia, rb, ib, coef, lane);
    stage_intra<1, 2>(ra, ia, rb, ib, coef, lane);

    stage_shfl<2>(ra, ia, rb, ib, coef, lane);
    stage_shfl<3>(ra, ia, rb, ib, coef, lane);
    stage_shfl<4>(ra, ia, rb, ib, coef, lane);
    stage_shfl<5>(ra, ia, rb, ib, coef, lane);
    stage_shfl<6>(ra, ia, rb, ib, coef, lane);
    stage_shfl<7>(ra, ia, rb, ib, coef, lane);

    stage_intra<8, 4>(ra, ia, rb, ib, coef, lane);
    stage_intra<9, 8>(ra, ia, rb, ib, coef, lane);

    float* o0 = out + rowbase * 2048 + lane * 4;
    float* o1 = o0 + 2048;
#pragma unroll
    for (int eh = 0; eh < 4; ++eh) {
        nfloat4 v0r = { ra[eh * 4 + 0], ra[eh * 4 + 1], ra[eh * 4 + 2], ra[eh * 4 + 3] };
        nfloat4 v0i = { ia[eh * 4 + 0], ia[eh * 4 + 1], ia[eh * 4 + 2], ia[eh * 4 + 3] };
        nfloat4 v1r = { rb[eh * 4 + 0], rb[eh * 4 + 1], rb[eh * 4 + 2], rb[eh * 4 + 3] };
        nfloat4 v1i = { ib[eh * 4 + 0], ib[eh * 4 + 1], ib[eh * 4 + 2], ib[eh * 4 + 3] };
        __builtin_nontemporal_store(v0r, (nfloat4*)(o0 + eh * 256));
        __builtin_nontemporal_store(v0i, (nfloat4*)(o0 + 1024 + eh * 256));
        __builtin_nontemporal_store(v1r, (nfloat4*)(o1 + eh * 256));
        __builtin_nontemporal_store(v1i, (nfloat4*)(o1 + 1024 + eh * 256));
    }
}

extern "C" void kernel_launch(void* const* d_in, const int* in_sizes, int n_in,
                              void* d_out, int out_size, void* d_ws, size_t ws_size,
                              hipStream_t stream) {
    const float* X     = (const float*)d_in[0];
    const float* theta = (const float*)d_in[1];
    const float* phi   = (const float*)d_in[2];
    const float* psi   = (const float*)d_in[3];
    float4* coef = (float4*)d_ws;   // P*D*sizeof(float4) = 160 KB

    coef_kernel<<<(P * D + 255) / 256, 256, 0, stream>>>(theta, phi, psi, coef);
    fft_kernel<<<NROWS / 8, 256, 0, stream>>>(X, coef, (float*)d_out);
}

// Round 4
// 77.501 us; speedup vs baseline: 2.1935x; 2.1935x over previous
//
#include <hip/hip_runtime.h>

#define P 10
#define D 1024
#define NROWS 16384

typedef float nfloat4 __attribute__((ext_vector_type(4)));   // clang-native for nontemporal builtins

// ---------------------------------------------------------------------------
// Column mapping for the main kernel:
//   k = e_hi*256 + lane*4 + e_lo,  e = e_hi*4 + e_lo,  e in [0,16), lane in [0,64)
//   k bits: [1:0]=e_lo  [7:2]=lane  [9:8]=e_hi
// Stage j flips bit j of k:
//   j=0,1  -> e_lo bits  -> intra-thread, partner e^1 / e^2
//   j=2..7 -> lane bits  -> __shfl_xor with mask 1<<(j-2)
//   j=8,9  -> e_hi bits  -> intra-thread, partner e^4 / e^8
//
// Coef table is stored SWIZZLED to this mapping:
//   coef[j*D + e*64 + lane] = (u_re, u_im, v_re, v_im) for column k(e,lane)
// so every coef load is consecutive-lane coalesced (16B/lane contiguous).
// psi epilogue rotation is folded into the stage-9 coefficients.
// ---------------------------------------------------------------------------
__global__ void coef_kernel(const float* __restrict__ theta,
                            const float* __restrict__ phi,
                            const float* __restrict__ psi,
                            float4* __restrict__ coef) {
    int idx = blockIdx.x * blockDim.x + threadIdx.x;
    if (idx >= P * D) return;
    int j = idx >> 10;
    int slot = idx & (D - 1);
    int e = slot >> 6;
    int lane = slot & 63;
    int k = ((e >> 2) << 8) + (lane << 2) + (e & 3);   // column this slot serves
    int b = (k >> j) & 1;
    unsigned lowmask = (1u << j) - 1u;
    unsigned m = ((unsigned)k & lowmask) | (((unsigned)k >> 1) & ~lowmask); // delete bit j
    float th = theta[j * (D / 2) + m];
    float ph = phi[j * (D / 2) + m];
    float h = th * 0.5f;
    float s1 = sinf(h), c1 = cosf(h);
    float s2 = sinf(h + ph), c2 = cosf(h + ph);
    float ur, ui, vr, vi;
    if (b) { ur =  s1 * s1; vr = -c1 * s2; ui = -c1 * s1; vi = c1 * c2; }
    else   { ur = -s1 * s2; vr = -c1 * s1; ui =  s1 * c2; vi = c1 * c1; }
    if (j == P - 1) {
        float ps = psi[k];
        float cp = cosf(ps), sp = sinf(ps);
        float ur2 = cp * ur - sp * ui, ui2 = sp * ur + cp * ui;
        float vr2 = cp * vr - sp * vi, vi2 = sp * vr + cp * vi;
        ur = ur2; ui = ui2; vr = vr2; vi = vi2;
    }
    coef[idx] = make_float4(ur, ui, vr, vi);
}

// ---------------------------------------------------------------------------
// Intra-thread butterfly stage: partner differs in a bit of e (mask PM).
// ---------------------------------------------------------------------------
template <int J, int PM>
__device__ __forceinline__ void stage_intra(float (&ra)[16], float (&ia)[16],
                                            float (&rb)[16], float (&ib)[16],
                                            const float4* __restrict__ coef, int lane) {
    const float4* cj = coef + J * D + lane;
#pragma unroll
    for (int e0 = 0; e0 < 16; ++e0) {
        if (e0 & PM) continue;
        const int e1 = e0 | PM;
        float4 c0 = cj[e0 * 64];
        float4 c1 = cj[e1 * 64];
        float ar0 = ra[e0], ai0 = ia[e0], ar1 = ra[e1], ai1 = ia[e1];
        float br0 = rb[e0], bi0 = ib[e0], br1 = rb[e1], bi1 = ib[e1];
        ra[e0] = c0.x * ar0 - c0.y * ai0 + c0.z * ar1 - c0.w * ai1;
        ia[e0] = c0.x * ai0 + c0.y * ar0 + c0.z * ai1 + c0.w * ar1;
        ra[e1] = c1.x * ar1 - c1.y * ai1 + c1.z * ar0 - c1.w * ai0;
        ia[e1] = c1.x * ai1 + c1.y * ar1 + c1.z * ai0 + c1.w * ar0;
        rb[e0] = c0.x * br0 - c0.y * bi0 + c0.z * br1 - c0.w * bi1;
        ib[e0] = c0.x * bi0 + c0.y * br0 + c0.z * bi1 + c0.w * br1;
        rb[e1] = c1.x * br1 - c1.y * bi1 + c1.z * br0 - c1.w * bi0;
        ib[e1] = c1.x * bi1 + c1.y * br1 + c1.z * bi0 + c1.w * br0;
    }
}

// ---------------------------------------------------------------------------
// Cross-lane butterfly stage: partner differs in lane bit (J-2).
// ---------------------------------------------------------------------------
template <int J>
__device__ __forceinline__ void stage_shfl(float (&ra)[16], float (&ia)[16],
                                           float (&rb)[16], float (&ib)[16],
                                           const float4* __restrict__ coef, int lane) {
    const int mask = 1 << (J - 2);
    const float4* cj = coef + J * D + lane;
#pragma unroll
    for (int e = 0; e < 16; ++e) {
        float4 c = cj[e * 64];
        float sra = __shfl_xor(ra[e], mask);
        float sia = __shfl_xor(ia[e], mask);
        float srb = __shfl_xor(rb[e], mask);
        float sib = __shfl_xor(ib[e], mask);
        float nra = c.x * ra[e] - c.y * ia[e] + c.z * sra - c.w * sia;
        float nia = c.x * ia[e] + c.y * ra[e] + c.z * sia + c.w * sra;
        float nrb = c.x * rb[e] - c.y * ib[e] + c.z * srb - c.w * sib;
        float nib = c.x * ib[e] + c.y * rb[e] + c.z * sib + c.w * srb;
        ra[e] = nra; ia[e] = nia; rb[e] = nrb; ib[e] = nib;
    }
}

__global__ __launch_bounds__(256) void fft_kernel(const float* __restrict__ X,
                                                  const float4* __restrict__ coef,
                                                  float* __restrict__ out) {
    const int lane = threadIdx.x & 63;
    const int wave = threadIdx.x >> 6;
    const long rowbase = (long)blockIdx.x * 8 + (long)wave * 2;
    const float* x0 = X + rowbase * 2048 + lane * 4;
    const float* x1 = x0 + 2048;

    float ra[16], ia[16], rb[16], ib[16];
#pragma unroll
    for (int eh = 0; eh < 4; ++eh) {
        float4 v0r = *(const float4*)(x0 + eh * 256);
        float4 v0i = *(const float4*)(x0 + 1024 + eh * 256);
        float4 v1r = *(const float4*)(x1 + eh * 256);
        float4 v1i = *(const float4*)(x1 + 1024 + eh * 256);
        ra[eh * 4 + 0] = v0r.x; ra[eh * 4 + 1] = v0r.y; ra[eh * 4 + 2] = v0r.z; ra[eh * 4 + 3] = v0r.w;
        ia[eh * 4 + 0] = v0i.x; ia[eh * 4 + 1] = v0i.y; ia[eh * 4 + 2] = v0i.z; ia[eh * 4 + 3] = v0i.w;
        rb[eh * 4 + 0] = v1r.x; rb[eh * 4 + 1] = v1r.y; rb[eh * 4 + 2] = v1r.z; rb[eh * 4 + 3] = v1r.w;
        ib[eh * 4 + 0] = v1i.x; ib[eh * 4 + 1] = v1i.y; ib[eh * 4 + 2] = v1i.z; ib[eh * 4 + 3] = v1i.w;
    }

    stage_intra<0, 1>(ra, ia, rb, ib, coef, lane);
    stage_intra<1, 2>(ra, ia, rb, ib, coef, lane);

    stage_shfl<2>(ra, ia, rb, ib, coef, lane);
    stage_shfl<3>(ra, ia, rb, ib, coef, lane);
    stage_shfl<4>(ra, ia, rb, ib, coef, lane);
    stage_shfl<5>(ra, ia, rb, ib, coef, lane);
    stage_shfl<6>(ra, ia, rb, ib, coef, lane);
    stage_shfl<7>(ra, ia, rb, ib, coef, lane);

    stage_intra<8, 4>(ra, ia, rb, ib, coef, lane);
    stage_intra<9, 8>(ra, ia, rb, ib, coef, lane);

    float* o0 = out + rowbase * 2048 + lane * 4;
    float* o1 = o0 + 2048;
#pragma unroll
    for (int eh = 0; eh < 4; ++eh) {
        nfloat4 v0r = { ra[eh * 4 + 0], ra[eh * 4 + 1], ra[eh * 4 + 2], ra[eh * 4 + 3] };
        nfloat4 v0i = { ia[eh * 4 + 0], ia[eh * 4 + 1], ia[eh * 4 + 2], ia[eh * 4 + 3] };
        nfloat4 v1r = { rb[eh * 4 + 0], rb[eh * 4 + 1], rb[eh * 4 + 2], rb[eh * 4 + 3] };
        nfloat4 v1i = { ib[eh * 4 + 0], ib[eh * 4 + 1], ib[eh * 4 + 2], ib[eh * 4 + 3] };
        __builtin_nontemporal_store(v0r, (nfloat4*)(o0 + eh * 256));
        __builtin_nontemporal_store(v0i, (nfloat4*)(o0 + 1024 + eh * 256));
        __builtin_nontemporal_store(v1r, (nfloat4*)(o1 + eh * 256));
        __builtin_nontemporal_store(v1i, (nfloat4*)(o1 + 1024 + eh * 256));
    }
}

extern "C" void kernel_launch(void* const* d_in, const int* in_sizes, int n_in,
                              void* d_out, int out_size, void* d_ws, size_t ws_size,
                              hipStream_t stream) {
    const float* X     = (const float*)d_in[0];
    const float* theta = (const float*)d_in[1];
    const float* phi   = (const float*)d_in[2];
    const float* psi   = (const float*)d_in[3];
    float4* coef = (float4*)d_ws;   // P*D*sizeof(float4) = 160 KB

    coef_kernel<<<(P * D + 255) / 256, 256, 0, stream>>>(theta, phi, psi, coef);
    fft_kernel<<<NROWS / 8, 256, 0, stream>>>(X, coef, (float*)d_out);
}